// Round 3
// baseline (1787.727 us; speedup 1.0000x reference)
//
#include <hip/hip_runtime.h>

typedef _Float16 hf;
typedef _Float16 hf4 __attribute__((ext_vector_type(4)));
typedef _Float16 hf8 __attribute__((ext_vector_type(8)));
typedef float f4 __attribute__((ext_vector_type(4)));

#define NTH 512
// LDS map (bytes)
#define ACT_OFF   0        // 32768: activations, packed 16x32 f16 tiles (m=s, k=f)
#define WB_OFF    32768    // 32768: staged packed weights
#define XB1_OFF   65536    // 32768: H1 / P / D+bias scratch
#define XB2_OFF   98304    // 32768: OB / F1 chunk / cond-phase f32 misc
#define QB_OFF    131072   // 8192  Q packed (m=s,k=d)
#define KB_OFF    139264   // 8192  K packed (m=s,k=d)
#define VT_OFF    147456   // 8192  V^T packed (m=d,k=s)
#define MISC_OFF  155648   // 784 f32: comb[256], mwls[16], lnp[512]
#define SMEM_BYTES 158784

// d_ws packed-weight layout (in halves)
#define WSH_QKV 0          // [l][h] 12288
#define WSH_WO  98304      // [l] 16384
#define WSH_FW1 131072     // [l][ch] 16384
#define WSH_FW2 196608     // [l][ch] 16384
#define WSH_CW2 262144     // 8192
#define WSH_TOTAL 270336

__device__ __forceinline__ float dsilu(float x){ return x / (1.f + __expf(-x)); }
__device__ __forceinline__ float dtanh(float x){
  float xc = fminf(fmaxf(x, -10.f), 10.f);
  float e = __expf(2.f * xc);
  return (e - 1.f) / (e + 1.f);
}

// ---------------- prep: pack f32 weights -> f16 A-fragment tile order ----------------
__global__ void prep_pack(const float* __restrict__ wqkv, const float* __restrict__ wo,
                          const float* __restrict__ fw1, const float* __restrict__ fw2,
                          const float* __restrict__ cw2, hf* __restrict__ ws){
  int idx = blockIdx.x * 256 + threadIdx.x;
  if (idx >= WSH_TOTAL) return;
  float v;
  if (idx < WSH_WO){                       // qkv per (layer, head): K=128, N=96
    int u = idx; int lh = u / 12288; int l = lh >> 2, h = lh & 3;
    int r = u % 12288; int tl = r >> 9; int lane = (r >> 3) & 63; int j = r & 7;
    int q = lane >> 4, c = lane & 15;
    int tn = tl >> 2, tk = tl & 3;
    int k = tk*32 + q*8 + j, nloc = tn*16 + c;
    int gcol = (nloc >> 5)*128 + h*32 + (nloc & 31);
    v = wqkv[l*49152 + k*384 + gcol];
  } else if (idx < WSH_FW1){               // wo: K=128, N=128
    int u = idx - WSH_WO; int l = u >> 14; int r = u & 16383;
    int tl = r >> 9; int lane = (r >> 3) & 63; int j = r & 7;
    int q = lane >> 4, c = lane & 15;
    int tn = tl >> 2, tk = tl & 3;
    v = wo[l*16384 + (tk*32 + q*8 + j)*128 + tn*16 + c];
  } else if (idx < WSH_FW2){               // fw1 chunk ch: cols ch*128..+127
    int u = idx - WSH_FW1; int lch = u >> 14; int l = lch >> 1, ch = lch & 1; int r = u & 16383;
    int tl = r >> 9; int lane = (r >> 3) & 63; int j = r & 7;
    int q = lane >> 4, c = lane & 15;
    int tn = tl >> 2, tk = tl & 3;
    v = fw1[l*32768 + (tk*32 + q*8 + j)*256 + ch*128 + tn*16 + c];
  } else if (idx < WSH_CW2){               // fw2 k-chunk ch: rows ch*128..+127
    int u = idx - WSH_FW2; int lch = u >> 14; int l = lch >> 1, ch = lch & 1; int r = u & 16383;
    int tl = r >> 9; int lane = (r >> 3) & 63; int j = r & 7;
    int q = lane >> 4, c = lane & 15;
    int tn = tl >> 2, tk = tl & 3;
    v = fw2[l*32768 + (ch*128 + tk*32 + q*8 + j)*128 + tn*16 + c];
  } else {                                 // c_w2: K=64, N=128
    int u = idx - WSH_CW2;
    int tl = u >> 9; int lane = (u >> 3) & 63; int j = u & 7;
    int q = lane >> 4, c = lane & 15;
    int tn = tl >> 1, tk = tl & 1;
    v = cw2[(tk*32 + q*8 + j)*128 + tn*16 + c];
  }
  ws[idx] = (hf)v;
}

// ---------------- helpers ----------------
template<int NHALVES>
__device__ __forceinline__ void copy_ws(hf* dst, const hf* src, int t){
  const hf8* s8 = (const hf8*)src; hf8* d8 = (hf8*)dst;
#pragma unroll
  for (int i = 0; i < NHALVES/8/NTH; ++i) d8[i*NTH + t] = s8[i*NTH + t];
}

// GEMM: D[f][s] tiles. A = packed weights (m=f_out, k), B = packed acts (m=s, k).
// wave handles 2 s-tiles (2sp, 2sp+1) x NT n-tiles (np*NT..+NT-1).
template<int KT, int NT>
__device__ __forceinline__ void gemmT(f4 (&acc)[2][NT], const hf* Ap, const hf* Bp,
                                      int sp, int np, int lane){
#pragma unroll
  for (int tk = 0; tk < KT; ++tk){
    hf8 b0 = *(const hf8*)(Bp + (((2*sp  )*KT + tk) << 9) + lane*8);
    hf8 b1 = *(const hf8*)(Bp + (((2*sp+1)*KT + tk) << 9) + lane*8);
#pragma unroll
    for (int jn = 0; jn < NT; ++jn){
      hf8 a = *(const hf8*)(Ap + (((np*NT + jn)*KT + tk) << 9) + lane*8);
      acc[0][jn] = __builtin_amdgcn_mfma_f32_16x16x32_f16(a, b0, acc[0][jn], 0, 0, 0);
      acc[1][jn] = __builtin_amdgcn_mfma_f32_16x16x32_f16(a, b1, acc[1][jn], 0, 0, 0);
    }
  }
}

// store D-tile (f = ft*16+q*4+r, s = ts*16+c) into packed(m=s,k=f) buffer, one b64
__device__ __forceinline__ void store_packed_b64(hf* dst, int KtilesOut, int ts, int ft,
                                                 f4 v, int q, int c){
  int tk = ft >> 1;
  int qp = ((ft & 1) << 1) + (q >> 1);
  int j0 = (q & 1) << 2;
  hf4 h; h[0] = (hf)v[0]; h[1] = (hf)v[1]; h[2] = (hf)v[2]; h[3] = (hf)v[3];
  *(hf4*)(dst + ((ts*KtilesOut + tk) << 9) + ((qp*16 + c) << 3) + j0) = h;
}

// ACT = LN(ACT + D) over f (=128) for each s; thread = s*4 + p
__device__ __forceinline__ void ln_pass(hf* A, const hf* Dh, const float* g, const float* bb, int t){
  int s = t >> 2, p = t & 3;
  float xr[4][8];
  int offs[4];
  float sum = 0.f, sq = 0.f;
#pragma unroll
  for (int tk = 0; tk < 4; ++tk){
    int off = (((s >> 4) * 4 + tk) << 9) + ((p * 16 + (s & 15)) << 3);
    offs[tk] = off;
    hf8 va = *(const hf8*)(A + off);
    hf8 vd = *(const hf8*)(Dh + off);
#pragma unroll
    for (int j = 0; j < 8; ++j){
      float x = (float)va[j] + (float)vd[j];
      xr[tk][j] = x; sum += x; sq += x * x;
    }
  }
  sum += __shfl_xor(sum, 1); sq += __shfl_xor(sq, 1);
  sum += __shfl_xor(sum, 2); sq += __shfl_xor(sq, 2);
  float mean = sum * (1.f/128.f);
  float rstd = rsqrtf(sq * (1.f/128.f) - mean*mean + 1e-5f);
#pragma unroll
  for (int tk = 0; tk < 4; ++tk){
    hf8 y;
#pragma unroll
    for (int j = 0; j < 8; ++j){
      int f = tk*32 + p*8 + j;
      y[j] = (hf)((xr[tk][j] - mean) * rstd * g[f] + bb[f]);
    }
    *(hf8*)(A + offs[tk]) = y;
  }
}

// ---------------- fused main kernel: one block per batch ----------------
__global__ __launch_bounds__(NTH, 2) void fused_fp(
    const float* __restrict__ x, const int* __restrict__ timesteps, const float* __restrict__ cond,
    const float* __restrict__ t_w1, const float* __restrict__ t_b1,
    const float* __restrict__ t_w2, const float* __restrict__ t_b2,
    const float* __restrict__ c_w1, const float* __restrict__ c_b1,
    const float* __restrict__ c_b2,
    const float* __restrict__ bqkv_g, const float* __restrict__ bo_g,
    const float* __restrict__ ln1g_g, const float* __restrict__ ln1b_g,
    const float* __restrict__ fb1_g, const float* __restrict__ fb2_g,
    const float* __restrict__ ln2g_g, const float* __restrict__ ln2b_g,
    const float* __restrict__ mw_w1, const float* __restrict__ mw_b1,
    const float* __restrict__ mw_w2, const float* __restrict__ mw_b2,
    const float* __restrict__ s_w1, const float* __restrict__ s_b1,
    const float* __restrict__ s_w2, const float* __restrict__ s_b2,
    const hf* __restrict__ wsp, float* __restrict__ out)
{
  extern __shared__ char smem[];
  hf* ACTh = (hf*)(smem + ACT_OFF);
  hf* WBh  = (hf*)(smem + WB_OFF);
  hf* XB1h = (hf*)(smem + XB1_OFF);
  hf* XB2h = (hf*)(smem + XB2_OFF);
  hf* QBh  = (hf*)(smem + QB_OFF);
  hf* KBh  = (hf*)(smem + KB_OFF);
  hf* VTh  = (hf*)(smem + VT_OFF);
  float* XB1f = (float*)(smem + XB1_OFF);
  float* XB2f = (float*)(smem + XB2_OFF);
  float* miscf = (float*)(smem + MISC_OFF);
  float* comb = miscf;          // 256
  float* mwls = miscf + 256;    // 16
  float* lnp  = miscf + 272;    // 512
  // cond-phase f32 (XB2): te[128], th[256], cst[768], cw1s[448]
  float* te = XB2f; float* th = XB2f + 128; float* cst = XB2f + 384; float* cw1s = XB2f + 1152;
  // student-phase f32 (QKV region)
  float* sw01 = (float*)(smem + QB_OFF);   // 1024
  float* sw2s = sw01 + 1024;               // 1024
  float* cvec = sw2s + 1024;               // 512

  const int b = blockIdx.x;
  const int t = threadIdx.x;
  const int w = t >> 6, lane = t & 63, q = lane >> 4, c = lane & 15;
  const int sp = w & 3, np = w >> 2;

  // ===== Phase 0: time features + cond staging =====
  if (t < 128){
    int i = t & 63;
    float f = __expf(-logf(10000.f) * (float)i * (1.f/64.f));
    float a = (float)timesteps[b] * f;
    te[t] = (t < 64) ? cosf(a) : sinf(a);
  }
  for (int idx = t; idx < 768; idx += NTH) cst[idx] = cond[b * 768 + idx];
  if (t < 384) cw1s[t] = c_w1[t];
  if (t < 64)  cw1s[384 + t] = c_b1[t];
  __syncthreads();

  // time MLP hidden; cond MLP layer1 -> H1 packed (XB1, Ktiles=2)
  if (t < 256){
    float a = t_b1[t];
    for (int i = 0; i < 128; ++i) a += te[i] * t_w1[i * 256 + t];
    th[t] = dsilu(a);
  }
  for (int idx = t; idx < 8192; idx += NTH){
    int s = idx >> 6, jf = idx & 63;
    float a = cw1s[384 + jf];
#pragma unroll
    for (int cc = 0; cc < 6; ++cc) a += cst[s * 6 + cc] * cw1s[cc * 64 + jf];
    XB1h[(((s >> 4)*2 + (jf >> 5)) << 9) + ((((jf & 31) >> 3)*16 + (s & 15)) << 3) + (jf & 7)] = (hf)dsilu(a);
  }
  __syncthreads();

  // time MLP out -> comb[0:128]; stage packed c_w2
  if (t < 128){
    float a = t_b2[t];
    for (int j = 0; j < 256; ++j) a += th[j] * t_w2[j * 128 + t];
    comb[t] = a;
  }
  copy_ws<8192>(WBh, wsp + WSH_CW2, t);
  __syncthreads();

  // cond MLP layer2 (MFMA) -> ACT packed
  {
    f4 acc[2][4]; 
#pragma unroll
    for (int i = 0; i < 2; ++i)
#pragma unroll
      for (int j = 0; j < 4; ++j){ f4 z = {0.f,0.f,0.f,0.f}; acc[i][j] = z; }
    gemmT<2,4>(acc, WBh, XB1h, sp, np, lane);
#pragma unroll
    for (int si = 0; si < 2; ++si)
#pragma unroll
      for (int jn = 0; jn < 4; ++jn){
        int ft = np*4 + jn, ts = 2*sp + si;
        f4 v = acc[si][jn];
#pragma unroll
        for (int r = 0; r < 4; ++r) v[r] = dsilu(v[r] + c_b2[ft*16 + q*4 + r]);
        store_packed_b64(ACTh, 4, ts, ft, v, q, c);
      }
  }
  __syncthreads();

  // ===== 2 transformer layers =====
  for (int l = 0; l < 2; ++l){
    if (t < 128){
      lnp[t]       = ln1g_g[l*128 + t];
      lnp[128 + t] = ln1b_g[l*128 + t];
      lnp[256 + t] = ln2g_g[l*128 + t];
      lnp[384 + t] = ln2b_g[l*128 + t];
    }
    f4 oacc[8];
#pragma unroll
    for (int i = 0; i < 8; ++i){ f4 z = {0.f,0.f,0.f,0.f}; oacc[i] = z; }

    for (int h = 0; h < 4; ++h){
      copy_ws<12288>(WBh, wsp + WSH_QKV + (l*4 + h)*12288, t);
      __syncthreads();
      // QKV GEMM (N=96): 2s x 3n
      {
        f4 acc[2][3];
#pragma unroll
        for (int i = 0; i < 2; ++i)
#pragma unroll
          for (int j = 0; j < 3; ++j){ f4 z = {0.f,0.f,0.f,0.f}; acc[i][j] = z; }
        gemmT<4,3>(acc, WBh, ACTh, sp, np, lane);
#pragma unroll
        for (int si = 0; si < 2; ++si)
#pragma unroll
          for (int jn = 0; jn < 3; ++jn){
            int ft = np*3 + jn, ts = 2*sp + si;
            int sel = ft >> 1;
            f4 v = acc[si][jn];
#pragma unroll
            for (int r = 0; r < 4; ++r)
              v[r] += bqkv_g[l*384 + sel*128 + h*32 + ((ft & 1)*16 + q*4 + r)];
            if (sel == 0){
#pragma unroll
              for (int r = 0; r < 4; ++r) v[r] *= 0.17677669529663687f;
              store_packed_b64(QBh, 1, ts, ft, v, q, c);
            } else if (sel == 1){
              store_packed_b64(KBh, 1, ts, ft - 2, v, q, c);
            } else {
              int td = ft - 4;
              int qp = ((ts & 1) << 1) + (c >> 3);
              hf* pb = VTh + ((td*4 + (ts >> 1)) << 9) + (c & 7);
#pragma unroll
              for (int r = 0; r < 4; ++r) pb[(qp*16 + q*4 + r) << 3] = (hf)v[r];
            }
          }
      }
      __syncthreads();
      // scores + softmax + P write (wave w owns q-tile w)
      {
        hf8 af = *(const hf8*)(QBh + (w << 9) + lane*8);
        f4 sc[8];
#pragma unroll
        for (int kst = 0; kst < 8; ++kst){
          hf8 bf = *(const hf8*)(KBh + (kst << 9) + lane*8);
          f4 z = {0.f,0.f,0.f,0.f};
          sc[kst] = __builtin_amdgcn_mfma_f32_16x16x32_f16(af, bf, z, 0, 0, 0);
        }
        float mr[4] = {-1e30f, -1e30f, -1e30f, -1e30f};
#pragma unroll
        for (int kst = 0; kst < 8; ++kst)
#pragma unroll
          for (int r = 0; r < 4; ++r) mr[r] = fmaxf(mr[r], sc[kst][r]);
#pragma unroll
        for (int r = 0; r < 4; ++r){
          mr[r] = fmaxf(mr[r], __shfl_xor(mr[r], 1));
          mr[r] = fmaxf(mr[r], __shfl_xor(mr[r], 2));
          mr[r] = fmaxf(mr[r], __shfl_xor(mr[r], 4));
          mr[r] = fmaxf(mr[r], __shfl_xor(mr[r], 8));
        }
        float ls[4] = {0.f, 0.f, 0.f, 0.f};
#pragma unroll
        for (int kst = 0; kst < 8; ++kst)
#pragma unroll
          for (int r = 0; r < 4; ++r){
            float e = __expf(sc[kst][r] - mr[r]);
            sc[kst][r] = e; ls[r] += e;
          }
#pragma unroll
        for (int r = 0; r < 4; ++r){
          ls[r] += __shfl_xor(ls[r], 1);
          ls[r] += __shfl_xor(ls[r], 2);
          ls[r] += __shfl_xor(ls[r], 4);
          ls[r] += __shfl_xor(ls[r], 8);
          ls[r] = 1.f / ls[r];
        }
#pragma unroll
        for (int kst = 0; kst < 8; ++kst){
          int qp = ((kst & 1) << 1) + (c >> 3);
          hf* pb = XB1h + ((w*4 + (kst >> 1)) << 9) + (c & 7);
#pragma unroll
          for (int r = 0; r < 4; ++r)
            pb[(qp*16 + q*4 + r) << 3] = (hf)(sc[kst][r] * ls[r]);
        }
      }
      // AV (same-wave P, barrier-free vs scores); accumulate into oacc
      {
#pragma unroll
        for (int ks = 0; ks < 4; ++ks){
          hf8 bp = *(const hf8*)(XB1h + ((w*4 + ks) << 9) + lane*8);
          hf8 a0 = *(const hf8*)(VTh + ((     ks) << 9) + lane*8);
          hf8 a1 = *(const hf8*)(VTh + ((4 +  ks) << 9) + lane*8);
          oacc[2*h]     = __builtin_amdgcn_mfma_f32_16x16x32_f16(a0, bp, oacc[2*h],     0, 0, 0);
          oacc[2*h + 1] = __builtin_amdgcn_mfma_f32_16x16x32_f16(a1, bp, oacc[2*h + 1], 0, 0, 0);
        }
      }
    } // heads

    // write attention output OB -> XB2 packed (wave w owns s-tile w)
#pragma unroll
    for (int ft = 0; ft < 8; ++ft) store_packed_b64(XB2h, 4, w, ft, oacc[ft], q, c);
    __syncthreads();

    // WO projection
    copy_ws<16384>(WBh, wsp + WSH_WO + l*16384, t);
    __syncthreads();
    {
      f4 acc[2][4];
#pragma unroll
      for (int i = 0; i < 2; ++i)
#pragma unroll
        for (int j = 0; j < 4; ++j){ f4 z = {0.f,0.f,0.f,0.f}; acc[i][j] = z; }
      gemmT<4,4>(acc, WBh, XB2h, sp, np, lane);
#pragma unroll
      for (int si = 0; si < 2; ++si)
#pragma unroll
        for (int jn = 0; jn < 4; ++jn){
          int ft = np*4 + jn, ts = 2*sp + si;
          f4 v = acc[si][jn];
#pragma unroll
          for (int r = 0; r < 4; ++r) v[r] += bo_g[l*128 + ft*16 + q*4 + r];
          store_packed_b64(XB1h, 4, ts, ft, v, q, c);
        }
    }
    __syncthreads();
    ln_pass(ACTh, XB1h, lnp, lnp + 128, t);
    __syncthreads();

    // FFN: two 128-col chunks; FFN2 accumulates in regs
    {
      f4 facc[2][4];
#pragma unroll
      for (int i = 0; i < 2; ++i)
#pragma unroll
        for (int j = 0; j < 4; ++j){ f4 z = {0.f,0.f,0.f,0.f}; facc[i][j] = z; }
      for (int ch = 0; ch < 2; ++ch){
        copy_ws<16384>(WBh, wsp + WSH_FW1 + (l*2 + ch)*16384, t);
        __syncthreads();
        {
          f4 acc[2][4];
#pragma unroll
          for (int i = 0; i < 2; ++i)
#pragma unroll
            for (int j = 0; j < 4; ++j){ f4 z = {0.f,0.f,0.f,0.f}; acc[i][j] = z; }
          gemmT<4,4>(acc, WBh, ACTh, sp, np, lane);
#pragma unroll
          for (int si = 0; si < 2; ++si)
#pragma unroll
            for (int jn = 0; jn < 4; ++jn){
              int ft = np*4 + jn, ts = 2*sp + si;
              f4 v = acc[si][jn];
#pragma unroll
              for (int r = 0; r < 4; ++r)
                v[r] = fmaxf(v[r] + fb1_g[l*256 + ch*128 + ft*16 + q*4 + r], 0.f);
              store_packed_b64(XB2h, 4, ts, ft, v, q, c);
            }
        }
        __syncthreads();
        copy_ws<16384>(WBh, wsp + WSH_FW2 + (l*2 + ch)*16384, t);
        __syncthreads();
        gemmT<4,4>(facc, WBh, XB2h, sp, np, lane);
        __syncthreads();
      }
#pragma unroll
      for (int si = 0; si < 2; ++si)
#pragma unroll
        for (int jn = 0; jn < 4; ++jn){
          int ft = np*4 + jn, ts = 2*sp + si;
          f4 v = facc[si][jn];
#pragma unroll
          for (int r = 0; r < 4; ++r) v[r] += fb2_g[l*128 + ft*16 + q*4 + r];
          store_packed_b64(XB1h, 4, ts, ft, v, q, c);
        }
    }
    __syncthreads();
    ln_pass(ACTh, XB1h, lnp + 256, lnp + 384, t);
    __syncthreads();
  } // layers

  // ===== cond_emb mean -> comb[128:256] =====
  {
    int f = t & 127, sg = t >> 7;
    float a = 0.f;
    for (int s2 = sg*32; s2 < sg*32 + 32; ++s2)
      a += (float)ACTh[(((s2 >> 4)*4 + (f >> 5)) << 9) + ((((f & 31) >> 3)*16 + (s2 & 15)) << 3) + (f & 7)];
    XB1f[t] = a;
  }
  __syncthreads();
  if (t < 128) comb[128 + t] = (XB1f[t] + XB1f[128 + t] + XB1f[256 + t] + XB1f[384 + t]) * (1.f/128.f);
  __syncthreads();

  // mixture hidden + stage student weights
  if (t < 128){
    float a = mw_b1[t];
    for (int i = 0; i < 256; ++i) a += comb[i] * mw_w1[i * 128 + t];
    XB1f[512 + t] = dsilu(a);
  }
  {
    int k = t >> 7, j = t & 127;
    sw01[t]       = s_w1[k * 33024 + j];
    sw01[512 + t] = s_w1[k * 33024 + 128 + j];
  }
  for (int idx = t; idx < 1024; idx += NTH) sw2s[idx] = s_w2[idx];
  __syncthreads();

  if (t < 4){
    float a = mw_b2[t];
    for (int j = 0; j < 128; ++j) a += XB1f[512 + j] * mw_w2[j * 4 + t];
    mwls[4 + t] = a;
  }
  __syncthreads();
  if (t == 0){
    float mx = fmaxf(fmaxf(mwls[4], mwls[5]), fmaxf(mwls[6], mwls[7]));
    float e0 = __expf(mwls[4] - mx), e1 = __expf(mwls[5] - mx);
    float e2 = __expf(mwls[6] - mx), e3 = __expf(mwls[7] - mx);
    float rs = 1.f / (e0 + e1 + e2 + e3);
    mwls[0] = e0 * rs; mwls[1] = e1 * rs; mwls[2] = e2 * rs; mwls[3] = e3 * rs;
  }
  {
    int k = t >> 7, j = t & 127;
    float a = s_b1[k * 128 + j];
    for (int i = 0; i < 256; ++i) a += comb[i] * s_w1[k * 33024 + (2 + i) * 128 + j];
    cvec[t] = a;
  }
  __syncthreads();

  // students: thread = (s, k)
  {
    int s2 = t >> 2, k = t & 3;
    float x0 = x[b * 256 + s2];
    float x1 = x[b * 256 + 128 + s2];
    float a0 = 0.f, a1 = 0.f;
    for (int j = 0; j < 128; ++j){
      float hk = dtanh(cvec[k * 128 + j] + x0 * sw01[k * 128 + j] + x1 * sw01[512 + k * 128 + j]);
      a0 += hk * sw2s[k * 256 + 2 * j];
      a1 += hk * sw2s[k * 256 + 2 * j + 1];
    }
    float mwk = mwls[k];
    float p0 = mwk * (a0 + s_b2[2 * k]);
    float p1 = mwk * (a1 + s_b2[2 * k + 1]);
    p0 += __shfl_xor(p0, 1); p0 += __shfl_xor(p0, 2);
    p1 += __shfl_xor(p1, 1); p1 += __shfl_xor(p1, 2);
    if (k == 0){
      out[b * 256 + s2]       = p0;
      out[b * 256 + 128 + s2] = p1;
    }
  }
}

extern "C" void kernel_launch(void* const* d_in, const int* in_sizes, int n_in,
                              void* d_out, int out_size, void* d_ws, size_t ws_size,
                              hipStream_t stream){
  (void)n_in; (void)ws_size; (void)out_size;
  hipFuncSetAttribute((const void*)fused_fp, hipFuncAttributeMaxDynamicSharedMemorySize, SMEM_BYTES);
  int B = in_sizes[1];
  hf* wsp = (hf*)d_ws;
  prep_pack<<<dim3((WSH_TOTAL + 255) / 256), dim3(256), 0, stream>>>(
      (const float*)d_in[11], (const float*)d_in[13], (const float*)d_in[17],
      (const float*)d_in[19], (const float*)d_in[9], wsp);
  fused_fp<<<dim3(B), dim3(NTH), SMEM_BYTES, stream>>>(
      (const float*)d_in[0], (const int*)d_in[1], (const float*)d_in[2],
      (const float*)d_in[3], (const float*)d_in[4], (const float*)d_in[5], (const float*)d_in[6],
      (const float*)d_in[7], (const float*)d_in[8], (const float*)d_in[10],
      (const float*)d_in[12], (const float*)d_in[14],
      (const float*)d_in[15], (const float*)d_in[16],
      (const float*)d_in[18], (const float*)d_in[20],
      (const float*)d_in[21], (const float*)d_in[22],
      (const float*)d_in[23], (const float*)d_in[24], (const float*)d_in[25], (const float*)d_in[26],
      (const float*)d_in[27], (const float*)d_in[28], (const float*)d_in[29], (const float*)d_in[30],
      wsp, (float*)d_out);
}

// Round 4
// 1201.342 us; speedup vs baseline: 1.4881x; 1.4881x over previous
//
#include <hip/hip_runtime.h>

typedef _Float16 hf;
typedef _Float16 hf4 __attribute__((ext_vector_type(4)));
typedef _Float16 hf8 __attribute__((ext_vector_type(8)));
typedef float f4 __attribute__((ext_vector_type(4)));

#define NTH 512
// LDS map (bytes)
#define ACT_OFF 0        // 32768: activations, packed 16x32 f16 tiles (m=s, k=f)
#define P_OFF   32768    // 8192: per-wave P tile (1 KB each)
#define SC_OFF  40960    // 32768: H1 / QKV bufs / OB / D / F1 / mean partials
#define SMEM_BYTES 73728

// d_ws packed-weight layout (halves) — prep_pack unchanged from R3 (verified)
#define WSH_QKV 0          // [l][h] 12288
#define WSH_WO  98304      // [l] 16384
#define WSH_FW1 131072     // [l][ch] 16384
#define WSH_FW2 196608     // [l][ch] 16384
#define WSH_CW2 262144     // 8192
#define WSH_TOTAL 270336
#define CEMB_BYTE_OFF 540672   // f32 cond_emb[B][128] in d_ws after packed weights

__device__ __forceinline__ float dsilu(float x){ return x / (1.f + __expf(-x)); }
__device__ __forceinline__ float dtanh(float x){
  float xc = fminf(fmaxf(x, -10.f), 10.f);
  float e = __expf(2.f * xc);
  return (e - 1.f) / (e + 1.f);
}

// ---------------- prep: pack f32 weights -> f16 A-fragment tile order ----------------
__global__ void prep_pack(const float* __restrict__ wqkv, const float* __restrict__ wo,
                          const float* __restrict__ fw1, const float* __restrict__ fw2,
                          const float* __restrict__ cw2, hf* __restrict__ ws){
  int idx = blockIdx.x * 256 + threadIdx.x;
  if (idx >= WSH_TOTAL) return;
  float v;
  if (idx < WSH_WO){
    int u = idx; int lh = u / 12288; int l = lh >> 2, h = lh & 3;
    int r = u % 12288; int tl = r >> 9; int lane = (r >> 3) & 63; int j = r & 7;
    int q = lane >> 4, c = lane & 15;
    int tn = tl >> 2, tk = tl & 3;
    int k = tk*32 + q*8 + j, nloc = tn*16 + c;
    int gcol = (nloc >> 5)*128 + h*32 + (nloc & 31);
    v = wqkv[l*49152 + k*384 + gcol];
  } else if (idx < WSH_FW1){
    int u = idx - WSH_WO; int l = u >> 14; int r = u & 16383;
    int tl = r >> 9; int lane = (r >> 3) & 63; int j = r & 7;
    int q = lane >> 4, c = lane & 15;
    int tn = tl >> 2, tk = tl & 3;
    v = wo[l*16384 + (tk*32 + q*8 + j)*128 + tn*16 + c];
  } else if (idx < WSH_FW2){
    int u = idx - WSH_FW1; int lch = u >> 14; int l = lch >> 1, ch = lch & 1; int r = u & 16383;
    int tl = r >> 9; int lane = (r >> 3) & 63; int j = r & 7;
    int q = lane >> 4, c = lane & 15;
    int tn = tl >> 2, tk = tl & 3;
    v = fw1[l*32768 + (tk*32 + q*8 + j)*256 + ch*128 + tn*16 + c];
  } else if (idx < WSH_CW2){
    int u = idx - WSH_FW2; int lch = u >> 14; int l = lch >> 1, ch = lch & 1; int r = u & 16383;
    int tl = r >> 9; int lane = (r >> 3) & 63; int j = r & 7;
    int q = lane >> 4, c = lane & 15;
    int tn = tl >> 2, tk = tl & 3;
    v = fw2[l*32768 + (ch*128 + tk*32 + q*8 + j)*128 + tn*16 + c];
  } else {
    int u = idx - WSH_CW2;
    int tl = u >> 9; int lane = (u >> 3) & 63; int j = u & 7;
    int q = lane >> 4, c = lane & 15;
    int tn = tl >> 1, tk = tl & 1;
    v = cw2[(tk*32 + q*8 + j)*128 + tn*16 + c];
  }
  ws[idx] = (hf)v;
}

// ---------------- helpers ----------------
// GEMM: wave owns one n-tile (nt), all 8 s-tiles. A from GLOBAL packed ws, B from LDS packed.
template<int KT>
__device__ __forceinline__ void gemmN(f4 (&acc)[8], const hf* __restrict__ Ag, const hf* Bh,
                                      int nt, int lane){
#pragma unroll
  for (int tk = 0; tk < KT; ++tk){
    hf8 a = *(const hf8*)(Ag + ((nt*KT + tk) << 9) + lane*8);
#pragma unroll
    for (int ts = 0; ts < 8; ++ts){
      hf8 b = *(const hf8*)(Bh + ((ts*KT + tk) << 9) + lane*8);
      acc[ts] = __builtin_amdgcn_mfma_f32_16x16x32_f16(a, b, acc[ts], 0, 0, 0);
    }
  }
}

// store D-tile (f = ft*16+q*4+r, s = ts*16+c) into packed(m=s,k=f) buffer, one b64
__device__ __forceinline__ void store_packed_b64(hf* dst, int KtilesOut, int ts, int ft,
                                                 f4 v, int q, int c){
  int tk = ft >> 1;
  int qp = ((ft & 1) << 1) + (q >> 1);
  int j0 = (q & 1) << 2;
  hf4 h; h[0] = (hf)v[0]; h[1] = (hf)v[1]; h[2] = (hf)v[2]; h[3] = (hf)v[3];
  *(hf4*)(dst + ((ts*KtilesOut + tk) << 9) + ((qp*16 + c) << 3) + j0) = h;
}

// ACT = LN(ACT + D); thread = s*4 + p ; gamma/beta read from global (L1-cached)
__device__ __forceinline__ void ln_pass(hf* A, const hf* Dh, const float* __restrict__ g,
                                        const float* __restrict__ bb, int t){
  int s = t >> 2, p = t & 3;
  float xr[4][8];
  int offs[4];
  float sum = 0.f, sq = 0.f;
#pragma unroll
  for (int tk = 0; tk < 4; ++tk){
    int off = (((s >> 4) * 4 + tk) << 9) + ((p * 16 + (s & 15)) << 3);
    offs[tk] = off;
    hf8 va = *(const hf8*)(A + off);
    hf8 vd = *(const hf8*)(Dh + off);
#pragma unroll
    for (int j = 0; j < 8; ++j){
      float x = (float)va[j] + (float)vd[j];
      xr[tk][j] = x; sum += x; sq += x * x;
    }
  }
  sum += __shfl_xor(sum, 1); sq += __shfl_xor(sq, 1);
  sum += __shfl_xor(sum, 2); sq += __shfl_xor(sq, 2);
  float mean = sum * (1.f/128.f);
  float rstd = rsqrtf(sq * (1.f/128.f) - mean*mean + 1e-5f);
#pragma unroll
  for (int tk = 0; tk < 4; ++tk){
    int f0 = tk*32 + p*8;
    f4 g0 = *(const f4*)(g + f0); f4 g1 = *(const f4*)(g + f0 + 4);
    f4 b0 = *(const f4*)(bb + f0); f4 b1 = *(const f4*)(bb + f0 + 4);
    hf8 y;
#pragma unroll
    for (int j = 0; j < 4; ++j){
      y[j]     = (hf)((xr[tk][j]     - mean) * rstd * g0[j] + b0[j]);
      y[j + 4] = (hf)((xr[tk][j + 4] - mean) * rstd * g1[j] + b1[j]);
    }
    *(hf8*)(A + offs[tk]) = y;
  }
}

// ---------------- main fused kernel: transformer part, one block per batch ----------------
__global__ __launch_bounds__(NTH, 4) void fused_fp(
    const float* __restrict__ cond,
    const float* __restrict__ c_w1, const float* __restrict__ c_b1, const float* __restrict__ c_b2,
    const float* __restrict__ bqkv_g, const float* __restrict__ bo_g,
    const float* __restrict__ ln1g_g, const float* __restrict__ ln1b_g,
    const float* __restrict__ fb1_g, const float* __restrict__ fb2_g,
    const float* __restrict__ ln2g_g, const float* __restrict__ ln2b_g,
    const hf* __restrict__ wsp, float* __restrict__ cemb)
{
  extern __shared__ char smem[];
  hf* ACTh = (hf*)(smem + ACT_OFF);
  hf* Ph   = (hf*)(smem + P_OFF);
  hf* SCh  = (hf*)(smem + SC_OFF);
  float* SCf = (float*)(smem + SC_OFF);
  // attention sub-buffers inside SC
  hf* Qh  = SCh;                 // 8192 B
  hf* Kh  = (hf*)(smem + SC_OFF + 8192);
  hf* VTh = (hf*)(smem + SC_OFF + 16384);
  // cond-phase f32 region inside SC (beyond H1's 16384 B)
  float* cst  = SCf + 4096;      // 768
  float* cw1s = SCf + 4096 + 768; // 448

  const int b = blockIdx.x;
  const int t = threadIdx.x;
  const int w = t >> 6, lane = t & 63, q = lane >> 4, c = lane & 15;
  const int sp = w & 3, np = w >> 2;

  // ===== cond staging =====
  for (int idx = t; idx < 768; idx += NTH) cst[idx] = cond[b * 768 + idx];
  if (t < 384) cw1s[t] = c_w1[t];
  if (t < 64)  cw1s[384 + t] = c_b1[t];
  __syncthreads();

  // cond MLP layer1 -> H1 packed in SC (Ktiles=2)
  for (int idx = t; idx < 8192; idx += NTH){
    int s = idx >> 6, jf = idx & 63;
    float a = cw1s[384 + jf];
#pragma unroll
    for (int cc = 0; cc < 6; ++cc) a += cst[s * 6 + cc] * cw1s[cc * 64 + jf];
    SCh[(((s >> 4)*2 + (jf >> 5)) << 9) + ((((jf & 31) >> 3)*16 + (s & 15)) << 3) + (jf & 7)] = (hf)dsilu(a);
  }
  __syncthreads();

  // cond MLP layer2 (MFMA, A from global packed) -> ACT
  {
    f4 acc[8];
#pragma unroll
    for (int i = 0; i < 8; ++i){ f4 z = {0.f,0.f,0.f,0.f}; acc[i] = z; }
    gemmN<2>(acc, wsp + WSH_CW2, SCh, w, lane);
    f4 cb = *(const f4*)(c_b2 + w*16 + q*4);
#pragma unroll
    for (int ts = 0; ts < 8; ++ts){
      f4 v = acc[ts];
#pragma unroll
      for (int r = 0; r < 4; ++r) v[r] = dsilu(v[r] + cb[r]);
      store_packed_b64(ACTh, 4, ts, w, v, q, c);
    }
  }

  // ===== 2 transformer layers =====
  for (int l = 0; l < 2; ++l){
    f4 oacc[8];
#pragma unroll
    for (int i = 0; i < 8; ++i){ f4 z = {0.f,0.f,0.f,0.f}; oacc[i] = z; }

    for (int h = 0; h < 4; ++h){
      __syncthreads();   // protect SC (prev readers done) before QKV epilogue writes
      // QKV GEMM: 2 s-tiles x 3 n-tiles per wave, A from global
      {
        const hf* Aq = wsp + WSH_QKV + (l*4 + h)*12288;
        f4 acc[2][3];
#pragma unroll
        for (int i = 0; i < 2; ++i)
#pragma unroll
          for (int j = 0; j < 3; ++j){ f4 z = {0.f,0.f,0.f,0.f}; acc[i][j] = z; }
#pragma unroll
        for (int tk = 0; tk < 4; ++tk){
          hf8 b0 = *(const hf8*)(ACTh + (((2*sp  )*4 + tk) << 9) + lane*8);
          hf8 b1 = *(const hf8*)(ACTh + (((2*sp+1)*4 + tk) << 9) + lane*8);
#pragma unroll
          for (int jn = 0; jn < 3; ++jn){
            hf8 a = *(const hf8*)(Aq + (((np*3 + jn)*4 + tk) << 9) + lane*8);
            acc[0][jn] = __builtin_amdgcn_mfma_f32_16x16x32_f16(a, b0, acc[0][jn], 0, 0, 0);
            acc[1][jn] = __builtin_amdgcn_mfma_f32_16x16x32_f16(a, b1, acc[1][jn], 0, 0, 0);
          }
        }
#pragma unroll
        for (int si = 0; si < 2; ++si)
#pragma unroll
          for (int jn = 0; jn < 3; ++jn){
            int ft = np*3 + jn, ts = 2*sp + si;
            int sel = ft >> 1;
            f4 v = acc[si][jn];
            f4 bq = *(const f4*)(bqkv_g + l*384 + sel*128 + h*32 + (ft & 1)*16 + q*4);
#pragma unroll
            for (int r = 0; r < 4; ++r) v[r] += bq[r];
            if (sel == 0){
#pragma unroll
              for (int r = 0; r < 4; ++r) v[r] *= 0.17677669529663687f;
              store_packed_b64(Qh, 1, ts, ft, v, q, c);
            } else if (sel == 1){
              store_packed_b64(Kh, 1, ts, ft - 2, v, q, c);
            } else {
              int td = ft - 4;
              int qp = ((ts & 1) << 1) + (c >> 3);
              hf* pb = VTh + ((td*4 + (ts >> 1)) << 9) + (c & 7);
#pragma unroll
              for (int r = 0; r < 4; ++r) pb[(qp*16 + q*4 + r) << 3] = (hf)v[r];
            }
          }
      }
      __syncthreads();
      // scores (a=K, b=Q -> D rows=kpos, col=qrow) + softmax + P(b64) + AV
      {
        hf8 qf = *(const hf8*)(Qh + (w << 9) + lane*8);
        f4 sc[8];
#pragma unroll
        for (int kst = 0; kst < 8; ++kst){
          hf8 kv = *(const hf8*)(Kh + (kst << 9) + lane*8);
          f4 z = {0.f,0.f,0.f,0.f};
          sc[kst] = __builtin_amdgcn_mfma_f32_16x16x32_f16(kv, qf, z, 0, 0, 0);
        }
        float m = -1e30f;
#pragma unroll
        for (int kst = 0; kst < 8; ++kst)
#pragma unroll
          for (int r = 0; r < 4; ++r) m = fmaxf(m, sc[kst][r]);
        m = fmaxf(m, __shfl_xor(m, 16));
        m = fmaxf(m, __shfl_xor(m, 32));
        float ls = 0.f;
#pragma unroll
        for (int kst = 0; kst < 8; ++kst)
#pragma unroll
          for (int r = 0; r < 4; ++r){
            float e = __expf(sc[kst][r] - m);
            sc[kst][r] = e; ls += e;
          }
        ls += __shfl_xor(ls, 16);
        ls += __shfl_xor(ls, 32);
        float rl = 1.f / ls;
        hf* Pw = Ph + (w << 9);
#pragma unroll
        for (int ks = 0; ks < 4; ++ks){
#pragma unroll
          for (int h2 = 0; h2 < 2; ++h2){
            int kst = 2*ks + h2;
            int qp = h2*2 + (q >> 1);
            int j0 = (q & 1) << 2;
            hf4 pv;
#pragma unroll
            for (int r = 0; r < 4; ++r) pv[r] = (hf)(sc[kst][r] * rl);
            *(hf4*)(Pw + qp*128 + c*8 + j0) = pv;
          }
          hf8 bp = *(const hf8*)(Pw + lane*8);
          hf8 a0 = *(const hf8*)(VTh + ((     ks) << 9) + lane*8);
          hf8 a1 = *(const hf8*)(VTh + ((4 +  ks) << 9) + lane*8);
          oacc[2*h]     = __builtin_amdgcn_mfma_f32_16x16x32_f16(a0, bp, oacc[2*h],     0, 0, 0);
          oacc[2*h + 1] = __builtin_amdgcn_mfma_f32_16x16x32_f16(a1, bp, oacc[2*h + 1], 0, 0, 0);
        }
      }
    } // heads

    __syncthreads();   // all waves done reading Q/K/VT
    // OB -> SC packed (wave w owns s-tile w; D rows = d-dim)
#pragma unroll
    for (int ft = 0; ft < 8; ++ft) store_packed_b64(SCh, 4, w, ft, oacc[ft], q, c);
    __syncthreads();

    // WO projection (reads OB in SC)
    {
      f4 acc[8];
#pragma unroll
      for (int i = 0; i < 8; ++i){ f4 z = {0.f,0.f,0.f,0.f}; acc[i] = z; }
      gemmN<4>(acc, wsp + WSH_WO + l*16384, SCh, w, lane);
      __syncthreads();   // done reading OB; now overwrite with D
      f4 bo = *(const f4*)(bo_g + l*128 + w*16 + q*4);
#pragma unroll
      for (int ts = 0; ts < 8; ++ts){
        f4 v = acc[ts];
#pragma unroll
        for (int r = 0; r < 4; ++r) v[r] += bo[r];
        store_packed_b64(SCh, 4, ts, w, v, q, c);
      }
    }
    __syncthreads();
    ln_pass(ACTh, SCh, ln1g_g + l*128, ln1b_g + l*128, t);
    __syncthreads();

    // FFN: two 128-col chunks; FFN2 accumulates in regs
    {
      f4 facc[8];
#pragma unroll
      for (int i = 0; i < 8; ++i){ f4 z = {0.f,0.f,0.f,0.f}; facc[i] = z; }
      for (int ch = 0; ch < 2; ++ch){
        f4 acc[8];
#pragma unroll
        for (int i = 0; i < 8; ++i){ f4 z = {0.f,0.f,0.f,0.f}; acc[i] = z; }
        gemmN<4>(acc, wsp + WSH_FW1 + (l*2 + ch)*16384, ACTh, w, lane);
        f4 fb = *(const f4*)(fb1_g + l*256 + ch*128 + w*16 + q*4);
#pragma unroll
        for (int ts = 0; ts < 8; ++ts){
          f4 v = acc[ts];
#pragma unroll
          for (int r = 0; r < 4; ++r) v[r] = fmaxf(v[r] + fb[r], 0.f);
          store_packed_b64(SCh, 4, ts, w, v, q, c);
        }
        __syncthreads();
        gemmN<4>(facc, wsp + WSH_FW2 + (l*2 + ch)*16384, SCh, w, lane);
        __syncthreads();   // done reading F1 chunk
      }
      f4 fb2 = *(const f4*)(fb2_g + l*128 + w*16 + q*4);
#pragma unroll
      for (int ts = 0; ts < 8; ++ts){
        f4 v = facc[ts];
#pragma unroll
        for (int r = 0; r < 4; ++r) v[r] += fb2[r];
        store_packed_b64(SCh, 4, ts, w, v, q, c);
      }
    }
    __syncthreads();
    ln_pass(ACTh, SCh, ln2g_g + l*128, ln2b_g + l*128, t);
    __syncthreads();
  } // layers

  // ===== cond_emb mean over s -> cemb (f32, in ws) =====
  {
    int o = t & 15;            // f-octet
    float fs[8];
#pragma unroll
    for (int j = 0; j < 8; ++j) fs[j] = 0.f;
#pragma unroll
    for (int u = 0; u < 4; ++u){
      int s = (t >> 4)*4 + u;
      hf8 v = *(const hf8*)(ACTh + (((s >> 4)*4 + (o >> 2)) << 9) + (((o & 3)*16 + (s & 15)) << 3));
#pragma unroll
      for (int j = 0; j < 8; ++j) fs[j] += (float)v[j];
    }
#pragma unroll
    for (int j = 0; j < 8; ++j){
      fs[j] += __shfl_xor(fs[j], 16);
      fs[j] += __shfl_xor(fs[j], 32);
    }
    if (lane < 16){
      f4 v0, v1;
#pragma unroll
      for (int j = 0; j < 4; ++j){ v0[j] = fs[j]; v1[j] = fs[j+4]; }
      *(f4*)(SCf + w*128 + o*8)     = v0;
      *(f4*)(SCf + w*128 + o*8 + 4) = v1;
    }
  }
  __syncthreads();
  if (t < 128){
    float a = 0.f;
#pragma unroll
    for (int wv = 0; wv < 8; ++wv) a += SCf[wv*128 + t];
    cemb[b*128 + t] = a * (1.f/128.f);
  }
}

// ---------------- tail kernel: batch-level phases, 8 batches per block ----------------
__global__ __launch_bounds__(256, 4) void tail_k(
    const float* __restrict__ x, const int* __restrict__ tstep, const float* __restrict__ cemb,
    const float* __restrict__ t_w1, const float* __restrict__ t_b1,
    const float* __restrict__ t_w2, const float* __restrict__ t_b2,
    const float* __restrict__ mw_w1, const float* __restrict__ mw_b1,
    const float* __restrict__ mw_w2, const float* __restrict__ mw_b2,
    const float* __restrict__ s_w1, const float* __restrict__ s_b1,
    const float* __restrict__ s_w2, const float* __restrict__ s_b2,
    float* __restrict__ out)
{
  __shared__ float sw01[1024], sw2[1024];
  __shared__ float te[128], th[256], comb[256], mwh[128], mwls[8], cvec[512], okp[1024];
  const int t = threadIdx.x;

  for (int i = t; i < 1024; i += 256){
    int row = i >> 9, k = (i >> 7) & 3, j = i & 127;
    sw01[i] = s_w1[k*33024 + row*128 + j];
    sw2[i]  = s_w2[i];
  }
  __syncthreads();

  for (int bi = 0; bi < 8; ++bi){
    int b = blockIdx.x * 8 + bi;
    if (t < 128){
      int i = t & 63;
      float f = __expf(-logf(10000.f) * (float)i * (1.f/64.f));
      float a = (float)tstep[b] * f;
      te[t] = (t < 64) ? cosf(a) : sinf(a);
    }
    __syncthreads();
    {
      float a = t_b1[t];
      for (int i = 0; i < 128; ++i) a += te[i] * t_w1[i*256 + t];
      th[t] = dsilu(a);
    }
    __syncthreads();
    if (t < 128){
      float a = t_b2[t];
      for (int j = 0; j < 256; ++j) a += th[j] * t_w2[j*128 + t];
      comb[t] = a;
    } else {
      comb[t] = cemb[b*128 + t - 128];
    }
    __syncthreads();
    if (t < 128){
      float a = mw_b1[t];
      for (int i = 0; i < 256; ++i) a += comb[i] * mw_w1[i*128 + t];
      mwh[t] = dsilu(a);
    }
#pragma unroll
    for (int u = 0; u < 2; ++u){
      int o = t + u*256; int k = o >> 7, j = o & 127;
      float a = s_b1[k*128 + j];
      for (int i = 0; i < 256; ++i) a += comb[i] * s_w1[k*33024 + (2 + i)*128 + j];
      cvec[o] = a;
    }
    __syncthreads();
    if (t < 4){
      float a = mw_b2[t];
      for (int j = 0; j < 128; ++j) a += mwh[j] * mw_w2[j*4 + t];
      mwls[4 + t] = a;
    }
    __syncthreads();
    if (t == 0){
      float mx = fmaxf(fmaxf(mwls[4], mwls[5]), fmaxf(mwls[6], mwls[7]));
      float e0 = __expf(mwls[4] - mx), e1 = __expf(mwls[5] - mx);
      float e2 = __expf(mwls[6] - mx), e3 = __expf(mwls[7] - mx);
      float rs = 1.f / (e0 + e1 + e2 + e3);
      mwls[0] = e0*rs; mwls[1] = e1*rs; mwls[2] = e2*rs; mwls[3] = e3*rs;
    }
    // students: item = (k, s); k uniform per 128 threads -> broadcast LDS reads
#pragma unroll
    for (int u = 0; u < 2; ++u){
      int o = t + u*256; int k = o >> 7, s = o & 127;
      float x0 = x[b*256 + s];
      float x1 = x[b*256 + 128 + s];
      float a0 = 0.f, a1 = 0.f;
      for (int j = 0; j < 128; ++j){
        float hk = dtanh(cvec[k*128 + j] + x0*sw01[k*128 + j] + x1*sw01[512 + k*128 + j]);
        a0 += hk * sw2[k*256 + 2*j];
        a1 += hk * sw2[k*256 + 2*j + 1];
      }
      okp[k*256 + s]       = a0 + s_b2[2*k];
      okp[k*256 + 128 + s] = a1 + s_b2[2*k + 1];
    }
    __syncthreads();
    {
      int row = t >> 7, s = t & 127;
      float a = 0.f;
#pragma unroll
      for (int k = 0; k < 4; ++k) a += mwls[k] * okp[k*256 + row*128 + s];
      out[b*256 + row*128 + s] = a;
    }
    __syncthreads();
  }
}

extern "C" void kernel_launch(void* const* d_in, const int* in_sizes, int n_in,
                              void* d_out, int out_size, void* d_ws, size_t ws_size,
                              hipStream_t stream){
  (void)n_in; (void)ws_size; (void)out_size;
  hipFuncSetAttribute((const void*)fused_fp, hipFuncAttributeMaxDynamicSharedMemorySize, SMEM_BYTES);
  int B = in_sizes[1];
  hf* wsp = (hf*)d_ws;
  float* cemb = (float*)((char*)d_ws + CEMB_BYTE_OFF);
  prep_pack<<<dim3((WSH_TOTAL + 255) / 256), dim3(256), 0, stream>>>(
      (const float*)d_in[11], (const float*)d_in[13], (const float*)d_in[17],
      (const float*)d_in[19], (const float*)d_in[9], wsp);
  fused_fp<<<dim3(B), dim3(NTH), SMEM_BYTES, stream>>>(
      (const float*)d_in[2],
      (const float*)d_in[7], (const float*)d_in[8], (const float*)d_in[10],
      (const float*)d_in[12], (const float*)d_in[14],
      (const float*)d_in[15], (const float*)d_in[16],
      (const float*)d_in[18], (const float*)d_in[20],
      (const float*)d_in[21], (const float*)d_in[22],
      wsp, cemb);
  tail_k<<<dim3(B / 8), dim3(256), 0, stream>>>(
      (const float*)d_in[0], (const int*)d_in[1], cemb,
      (const float*)d_in[3], (const float*)d_in[4], (const float*)d_in[5], (const float*)d_in[6],
      (const float*)d_in[23], (const float*)d_in[24], (const float*)d_in[25], (const float*)d_in[26],
      (const float*)d_in[27], (const float*)d_in[28], (const float*)d_in[29], (const float*)d_in[30],
      (float*)d_out);
}